// Round 8
// baseline (109.133 us; speedup 1.0000x reference)
//
#include <hip/hip_runtime.h>

// Problem constants (match reference)
#define NB 8
#define HH 352
#define WW 352
#define TX 32
#define TY 32
// AoS tap tile: taps look down/sideways only -> rows gy in [y0, y0+36],
// cols gx in [x0-5, x0+36].
#define TLH 37
#define TLW 42
#define LSTRIDE 43               // float4 units, odd -> (3*row + col) mod 8 covers all bank quads
// mask plane: rows gy in [y0, y0+36], cols gx in [x0-5, x0+36]
#define MH 37
#define MW 42
#define MSTRIDE 44               // mult of 4 floats for aligned b128 reads
#define TILES_X 11
#define TILES_Y 11
#define NBLK (TILES_X * TILES_Y * NB)   // 968

// Pre-scale rgb by sqrt(ALPHA * log2(e)) so wgt = exp2(-sum(d^2))
#define RGB_SCALE 16.98644781888824f

typedef float f32x2 __attribute__((ext_vector_type(2)));

__device__ __forceinline__ float elem(float4 q, int c) {
    return c == 0 ? q.x : c == 1 ? q.y : c == 2 ? q.z : q.w;
}

// One window float4 vs a PAIR of pre-negated packed centers, with mask-weight mq
// (mq = mask of the shared window pixel q). v = e*|ds| per tap;
// accP += v (m_p applied after the loop); accQ += v*mq.
__device__ __forceinline__ void tap_pair(const float4& w, float mq,
                                         f32x2 ncx, f32x2 ncy, f32x2 ncz, f32x2 ncw,
                                         f32x2& accP, f32x2& accQ) {
    f32x2 d0 = ncx + w.x;        // pk_add, scalar broadcast
    f32x2 d1 = ncy + w.y;
    f32x2 d2 = ncz + w.z;
    f32x2 s  = d0 * d0;
    s += d1 * d1;                // pk_fma
    s += d2 * d2;
    f32x2 ds = ncw + w.w;
    f32x2 v;
    v.x = __builtin_amdgcn_exp2f(-s.x) * fabsf(ds.x);
    v.y = __builtin_amdgcn_exp2f(-s.y) * fabsf(ds.y);
    accP += v;                   // pk_add
    f32x2 mqv; mqv.x = mq; mqv.y = mq;
    accQ += v * mqv;             // pk_fma
}

__device__ __forceinline__ void tap_scalar(const float4& w, float mq,
                                           float ncx, float ncy, float ncz, float ncw,
                                           float& aP, float& aQ) {
    float d0 = w.x + ncx, d1 = w.y + ncy, d2 = w.z + ncz;
    float s = fmaf(d0, d0, fmaf(d1, d1, d2 * d2));
    float v = __builtin_amdgcn_exp2f(-s) * fabsf(w.w + ncw);
    aP += v;
    aQ = fmaf(v, mq, aQ);
}

// LDS budget: tile 25456 + maskp 6512 + bitplanes 952 + wred 32 ~= 33 KB
// -> 4 blocks/CU by LDS. Launch bounds (256,2): R6 showed (256,4) forces a
// 64-VGPR cap -> scratch spills; (256,2) lets the allocator pick ~76-96 VGPR.
__global__ __launch_bounds__(256, 2)
void btm_loss_kernel(const float* __restrict__ pred,
                     const float* __restrict__ feat,
                     float2* __restrict__ partials,
                     unsigned* __restrict__ counter,
                     float* __restrict__ out) {
    __shared__ __align__(16) float4 tile[TLH * LSTRIDE];  // 25.4 KB AoS (r,g,b,sal)
    __shared__ __align__(16) float  maskp[MH * MSTRIDE];  // 6.5 KB mask plane
    __shared__ unsigned long long hbuf[41];               // horiz 5-OR of lbl bits
    __shared__ unsigned long long nhbuf[41];              // horiz 5-OR of ~lbl bits
    __shared__ unsigned long long Mbuf[37];               // final mask bits per row
    __shared__ float2 wred[4];
    __shared__ int islast;

    const int bid = blockIdx.x;
    const int tx_blk = bid % TILES_X;
    const int ty_blk = (bid / TILES_X) % TILES_Y;
    const int n = bid / (TILES_X * TILES_Y);
    const int x0 = tx_blk * TX;
    const int y0 = ty_blk * TY;

    const size_t plane = (size_t)HH * WW;
    const float* fr = feat + ((size_t)n * 3 + 0) * plane;
    const float* fg = feat + ((size_t)n * 3 + 1) * plane;
    const float* fb = feat + ((size_t)n * 3 + 2) * plane;
    const float* ps = pred + (size_t)n * plane;

    const int t = threadIdx.x;

    // ---- bit-mask build: one sal row per wave-iteration via ballot ----
    // Row r covers gy = y0+r-2, bit l covers gx = x0-7+l (l < 46). Validity is
    // folded into the ballot predicate (invalid -> contributes to neither OR,
    // matching maxpool's -inf padding / ero's min-over-valid).
    {
        const int wv = t >> 6, ln = t & 63;
        for (int r = wv; r < 41; r += 4) {
            int gy = y0 + r - 2;
            int gx = x0 - 7 + ln;
            bool inimg = ((unsigned)gy < (unsigned)HH) &&
                         ((unsigned)gx < (unsigned)WW) && (ln < 46);
            float sv = inimg ? ps[gy * WW + gx] : 0.f;
            unsigned long long lb = __ballot(inimg && (sv > 0.5f));
            unsigned long long nb = __ballot(inimg && (sv <= 0.5f));
            // horizontal OR over bits i..i+4 (result bit i <-> mask col i)
            unsigned long long a2 = lb | (lb >> 1); a2 |= (a2 >> 2); a2 |= (lb >> 4);
            unsigned long long b2 = nb | (nb >> 1); b2 |= (b2 >> 2); b2 |= (nb >> 4);
            if (ln == 0) { hbuf[r] = a2; nhbuf[r] = b2; }
        }
    }

    // ---- stage tap tile (no top halo, 5 left/right; rgb pre-scaled) ----
    for (int i = t; i < TLH * TLW; i += 256) {
        int lr = i / TLW;
        int lc = i - lr * TLW;
        int gy = y0 + lr;
        int gx = x0 + lc - 5;
        float4 v = make_float4(0.f, 0.f, 0.f, 0.f);
        if ((unsigned)gy < (unsigned)HH && (unsigned)gx < (unsigned)WW) {
            int gi = gy * WW + gx;
            v.x = fr[gi] * RGB_SCALE;
            v.y = fg[gi] * RGB_SCALE;
            v.z = fb[gi] * RGB_SCALE;
            v.w = ps[gi];
        }
        tile[lr * LSTRIDE + lc] = v;
    }
    __syncthreads();

    // ---- vertical 5-OR + q-position validity -> mask bits per row ----
    // mask(q)=1 iff dil=1 AND ero=0 <=> D & E (E = OR of valid ~lbl = 1-ero).
    if (t < 37) {
        int lo = 5 - x0; if (lo < 0) lo = 0;          // colmask: 0 <= x0-5+i < WW
        int hi = WW + 5 - x0; if (hi > 42) hi = 42;
        unsigned long long cm = ((1ull << hi) - 1) & ~((1ull << lo) - 1);
        unsigned long long D = hbuf[t], E = nhbuf[t];
        #pragma unroll
        for (int k = 1; k < 5; ++k) { D |= hbuf[t + k]; E |= nhbuf[t + k]; }
        Mbuf[t] = (y0 + t < HH) ? (D & E & cm) : 0ull;
    }
    __syncthreads();

    // ---- expand mask bits -> float plane (cols 0..41; 42-43 unused) ----
    for (int i = t; i < MH * MW; i += 256) {
        int mr = i / MW, mc = i - mr * MW;
        maskp[mr * MSTRIDE + mc] = (float)((Mbuf[mr] >> mc) & 1ull);
    }
    __syncthreads();

    // ---- half-window pair taps: each thread owns 4 x-adjacent pixels ----
    const int txq = t & 7;       // 0..7
    const int ty  = t >> 3;      // 0..31
    const int px0 = txq * 4;

    // trow[dy*LSTRIDE + j] = window col j (gx = x0+px0-5+j) of window row dy
    // (gy = y0+ty+dy). Centers at j = 5..8.
    const float4* trow = tile + ty * LSTRIDE + px0;
    const float*  mrow = maskp + ty * MSTRIDE + px0;   // mask col px0+j <-> window col j

    float4 c0 = trow[5], c1 = trow[6], c2 = trow[7], c3 = trow[8];
    f32x2 n01x = {-c0.x, -c1.x}, n01y = {-c0.y, -c1.y}, n01z = {-c0.z, -c1.z}, n01w = {-c0.w, -c1.w};
    f32x2 n23x = {-c2.x, -c3.x}, n23y = {-c2.y, -c3.y}, n23z = {-c2.z, -c3.z}, n23w = {-c2.w, -c3.w};

    f32x2 aP01 = {0.f, 0.f}, aP23 = {0.f, 0.f};
    f32x2 aQ01 = {0.f, 0.f}, aQ23 = {0.f, 0.f};
    float sP0 = 0.f, sP1 = 0.f, sP2 = 0.f, sP3 = 0.f, sQ = 0.f;

    // dy = 0 row: pairs to the RIGHT only (dx 1..5). Window cols j = 6..13.
    float4 mf0[3];
    #pragma unroll
    for (int q = 0; q < 3; ++q) mf0[q] = *(const float4*)&mrow[4 + 4 * q];
    {
        float4 w0[8];
        #pragma unroll
        for (int j = 0; j < 8; ++j) w0[j] = trow[6 + j];

        tap_scalar(w0[0], elem(mf0[0], 2), n01x.x, n01y.x, n01z.x, n01w.x, sP0, sQ); // c0 dx=1
        #pragma unroll
        for (int j = 1; j <= 4; ++j)  // c0 dx 2..5 / c1 dx 1..4
            tap_pair(w0[j], elem(mf0[(j + 2) >> 2], (j + 2) & 3), n01x, n01y, n01z, n01w, aP01, aQ01);
        tap_scalar(w0[5], elem(mf0[1], 3), n01x.y, n01y.y, n01z.y, n01w.y, sP1, sQ); // c1 dx=5
        tap_scalar(w0[2], elem(mf0[1], 0), n23x.x, n23y.x, n23z.x, n23w.x, sP2, sQ); // c2 dx=1
        #pragma unroll
        for (int j = 3; j <= 6; ++j)  // c2 dx 2..5 / c3 dx 1..4
            tap_pair(w0[j], elem(mf0[(j + 2) >> 2], (j + 2) & 3), n23x, n23y, n23z, n23w, aP23, aQ23);
        tap_scalar(w0[7], elem(mf0[2], 1), n23x.y, n23y.y, n23z.y, n23w.y, sP3, sQ); // c3 dx=5
    }

    // dy = 1..5 rows: full dx range [-5,5]. Window cols j = 0..13 (14 b128).
    // KEEP ROLLED (unroll 1): full unroll hoists ~70 float4 LDS loads ->
    // 280+ VGPR liveness -> scratch spill (R4: 8x slower).
    #pragma unroll 1
    for (int dy = 1; dy <= 5; ++dy) {
        float4 w[14];
        #pragma unroll
        for (int j = 0; j < 14; ++j) w[j] = trow[dy * LSTRIDE + j];
        float4 mf[4];
        const float* mro = mrow + dy * MSTRIDE;
        #pragma unroll
        for (int q = 0; q < 4; ++q) mf[q] = *(const float4*)&mro[4 * q];

        tap_scalar(w[0], elem(mf[0], 0), n01x.x, n01y.x, n01z.x, n01w.x, sP0, sQ); // c0 dx=-5
        #pragma unroll
        for (int j = 1; j <= 10; ++j)
            tap_pair(w[j], elem(mf[j >> 2], j & 3), n01x, n01y, n01z, n01w, aP01, aQ01);
        tap_scalar(w[11], elem(mf[2], 3), n01x.y, n01y.y, n01z.y, n01w.y, sP1, sQ); // c1 dx=+5
        tap_scalar(w[2],  elem(mf[0], 2), n23x.x, n23y.x, n23z.x, n23w.x, sP2, sQ); // c2 dx=-5
        #pragma unroll
        for (int j = 3; j <= 12; ++j)
            tap_pair(w[j], elem(mf[j >> 2], j & 3), n23x, n23y, n23z, n23w, aP23, aQ23);
        tap_scalar(w[13], elem(mf[3], 1), n23x.y, n23y.y, n23z.y, n23w.y, sP3, sQ); // c3 dx=+5
    }

    // ---- combine: num = sum_i m_i*(A_H(i) + pad_i) + sum(v*m_q) ----
    float m0 = mf0[0].y, m1 = mf0[0].z, m2 = mf0[0].w, m3 = mf0[1].x;
    float e0 = aP01.x + sP0, e1 = aP01.y + sP1;
    float e2 = aP23.x + sP2, e3 = aP23.y + sP3;

    // Upper/left pad taps (closed form): all pads identical for a pixel.
    const bool padblk = (ty_blk == 0) || (tx_blk == 0) || (tx_blk == TILES_X - 1);
    if (padblk) {
        const int gy = y0 + ty;
        const int nneg = (5 - gy) > 0 ? (5 - gy) : 0;   // # fully-pad rows above
        #pragma unroll
        for (int i = 0; i < 4; ++i) {
            const int gx = x0 + px0 + i;
            const int cl = (5 - gx) > 0 ? (5 - gx) : 0;
            const int cr = (gx - 346) > 0 ? (gx - 346) : 0;
            const int np = nneg * 11 + (5 - nneg) * (cl + cr) + cl;
            if (np > 0) {
                float4 ci = (i == 0) ? c0 : (i == 1) ? c1 : (i == 2) ? c2 : c3;
                float s2 = fmaf(ci.x, ci.x, fmaf(ci.y, ci.y, ci.z * ci.z));
                float vp = __builtin_amdgcn_exp2f(-s2) * ci.w * (float)np;
                if (i == 0) e0 += vp; else if (i == 1) e1 += vp;
                else if (i == 2) e2 += vp; else e3 += vp;
            }
        }
    }

    float num = fmaf(m0, e0, fmaf(m1, e1, fmaf(m2, e2, m3 * e3)))
              + ((aQ01.x + aQ01.y) + (aQ23.x + aQ23.y)) + sQ;
    float den = (m0 + m1) + (m2 + m3);

    // ---- wave reduce -> block reduce -> partial store ----
    #pragma unroll
    for (int off = 32; off > 0; off >>= 1) {
        num += __shfl_down(num, off, 64);
        den += __shfl_down(den, off, 64);
    }
    const int wid  = t >> 6;
    const int lane = t & 63;
    if (lane == 0) wred[wid] = make_float2(num, den);
    __syncthreads();
    if (t == 0) {
        float2 a = wred[0];
        #pragma unroll
        for (int w2 = 1; w2 < 4; ++w2) { a.x += wred[w2].x; a.y += wred[w2].y; }
        partials[bid] = a;
        __threadfence();                         // agent-scope release (L2 wb)
        unsigned old = atomicAdd(counter, 1u);   // device-scope by default
        islast = (old == (unsigned)(NBLK - 1)) ? 1 : 0;
    }
    __syncthreads();

    // ---- fused finalize: last-arriving block does the fixed-order reduction ----
    if (islast) {
        __threadfence();                         // acquire side (L2 inv)
        float fn = 0.f, fd = 0.f;
        for (int i = t; i < NBLK; i += 256) {
            float2 p = partials[i];
            fn += p.x;
            fd += p.y;
        }
        #pragma unroll
        for (int off = 32; off > 0; off >>= 1) {
            fn += __shfl_down(fn, off, 64);
            fd += __shfl_down(fd, off, 64);
        }
        if (lane == 0) wred[wid] = make_float2(fn, fd);
        __syncthreads();
        if (t == 0) {
            float2 a = wred[0];
            #pragma unroll
            for (int w2 = 1; w2 < 4; ++w2) { a.x += wred[w2].x; a.y += wred[w2].y; }
            out[0] = a.x / (a.y + 1e-6f);
        }
    }
}

extern "C" void kernel_launch(void* const* d_in, const int* in_sizes, int n_in,
                              void* d_out, int out_size, void* d_ws, size_t ws_size,
                              hipStream_t stream) {
    const float* pred = (const float*)d_in[0];  // (8,1,352,352) fp32
    const float* feat = (const float*)d_in[1];  // (8,3,352,352) fp32
    float* out = (float*)d_out;                 // scalar fp32
    float2* partials = (float2*)d_ws;           // NBLK float2 = 7.7 KB
    unsigned* counter = (unsigned*)((char*)d_ws + 8192);

    hipMemsetAsync(counter, 0, sizeof(unsigned), stream);  // capture-legal
    btm_loss_kernel<<<dim3(NBLK), dim3(256), 0, stream>>>(pred, feat, partials,
                                                          counter, out);
}

// Round 9
// 95.235 us; speedup vs baseline: 1.1459x; 1.1459x over previous
//
#include <hip/hip_runtime.h>

// Problem constants (match reference)
#define NB 8
#define HH 352
#define WW 352
#define TX 32
#define TY 32
// AoS tap tile: taps look down/sideways only -> rows gy in [y0, y0+36],
// cols gx in [x0-5, x0+36].
#define TLH 37
#define TLW 42
#define LSTRIDE 43               // float4 units, odd -> (3*row + col) mod 8 covers all bank quads
// mask plane: rows gy in [y0, y0+36], cols gx in [x0-5, x0+36]
#define MH 37
#define MW 42
#define MSTRIDE 44               // mult of 4 floats for aligned b128 reads
#define TILES_X 11
#define TILES_Y 11
#define NBLK (TILES_X * TILES_Y * NB)   // 968

// Pre-scale rgb by sqrt(ALPHA * log2(e)) so wgt = exp2(-sum(d^2))
#define RGB_SCALE 16.98644781888824f

typedef float f32x2 __attribute__((ext_vector_type(2)));

__device__ __forceinline__ float elem(float4 q, int c) {
    return c == 0 ? q.x : c == 1 ? q.y : c == 2 ? q.z : q.w;
}

// One window float4 vs a PAIR of pre-negated packed centers, with mask-weight mq
// (mq = mask of the shared window pixel q). v = e*|ds| per tap;
// accP += v (m_p applied after the loop); accQ += v*mq.
__device__ __forceinline__ void tap_pair(const float4& w, float mq,
                                         f32x2 ncx, f32x2 ncy, f32x2 ncz, f32x2 ncw,
                                         f32x2& accP, f32x2& accQ) {
    f32x2 d0 = ncx + w.x;        // pk_add, scalar broadcast
    f32x2 d1 = ncy + w.y;
    f32x2 d2 = ncz + w.z;
    f32x2 s  = d0 * d0;
    s += d1 * d1;                // pk_fma
    s += d2 * d2;
    f32x2 ds = ncw + w.w;
    f32x2 v;
    v.x = __builtin_amdgcn_exp2f(-s.x) * fabsf(ds.x);
    v.y = __builtin_amdgcn_exp2f(-s.y) * fabsf(ds.y);
    accP += v;                   // pk_add
    f32x2 mqv; mqv.x = mq; mqv.y = mq;
    accQ += v * mqv;             // pk_fma
}

__device__ __forceinline__ void tap_scalar(const float4& w, float mq,
                                           float ncx, float ncy, float ncz, float ncw,
                                           float& aP, float& aQ) {
    float d0 = w.x + ncx, d1 = w.y + ncy, d2 = w.z + ncz;
    float s = fmaf(d0, d0, fmaf(d1, d1, d2 * d2));
    float v = __builtin_amdgcn_exp2f(-s) * fabsf(w.w + ncw);
    aP += v;
    aQ = fmaf(v, mq, aQ);
}

// LDS budget: tile 25456 + maskp 6512 + bitplanes 952 + wred 32 ~= 33 KB
// -> 4 blocks/CU by LDS. Launch bounds (256,2): R6 showed (256,4) forces a
// 64-VGPR cap -> scratch spills; (256,2) lets the allocator pick ~76 VGPR.
// NO fused finalize: R8 showed per-block __threadfence (buffer_wbl2 for
// cross-XCD visibility) + 968-way atomic costs ~14 us; the separate 2 us
// finalize dispatch is far cheaper.
__global__ __launch_bounds__(256, 2)
void btm_loss_kernel(const float* __restrict__ pred,
                     const float* __restrict__ feat,
                     float2* __restrict__ partials) {
    __shared__ __align__(16) float4 tile[TLH * LSTRIDE];  // 25.4 KB AoS (r,g,b,sal)
    __shared__ __align__(16) float  maskp[MH * MSTRIDE];  // 6.5 KB mask plane
    __shared__ unsigned long long hbuf[41];               // horiz 5-OR of lbl bits
    __shared__ unsigned long long nhbuf[41];              // horiz 5-OR of ~lbl bits
    __shared__ unsigned long long Mbuf[37];               // final mask bits per row
    __shared__ float2 wred[4];

    const int bid = blockIdx.x;
    const int tx_blk = bid % TILES_X;
    const int ty_blk = (bid / TILES_X) % TILES_Y;
    const int n = bid / (TILES_X * TILES_Y);
    const int x0 = tx_blk * TX;
    const int y0 = ty_blk * TY;

    const size_t plane = (size_t)HH * WW;
    const float* fr = feat + ((size_t)n * 3 + 0) * plane;
    const float* fg = feat + ((size_t)n * 3 + 1) * plane;
    const float* fb = feat + ((size_t)n * 3 + 2) * plane;
    const float* ps = pred + (size_t)n * plane;

    const int t = threadIdx.x;

    // ---- bit-mask build: one sal row per wave-iteration via ballot ----
    // Row r covers gy = y0+r-2, bit l covers gx = x0-7+l (l < 46). Validity is
    // folded into the ballot predicate (invalid -> contributes to neither OR,
    // matching maxpool's zero padding / ero's min-over-valid).
    {
        const int wv = t >> 6, ln = t & 63;
        for (int r = wv; r < 41; r += 4) {
            int gy = y0 + r - 2;
            int gx = x0 - 7 + ln;
            bool inimg = ((unsigned)gy < (unsigned)HH) &&
                         ((unsigned)gx < (unsigned)WW) && (ln < 46);
            float sv = inimg ? ps[gy * WW + gx] : 0.f;
            unsigned long long lb = __ballot(inimg && (sv > 0.5f));
            unsigned long long nb = __ballot(inimg && (sv <= 0.5f));
            // horizontal OR over bits i..i+4 (result bit i <-> mask col i)
            unsigned long long a2 = lb | (lb >> 1); a2 |= (a2 >> 2); a2 |= (lb >> 4);
            unsigned long long b2 = nb | (nb >> 1); b2 |= (b2 >> 2); b2 |= (nb >> 4);
            if (ln == 0) { hbuf[r] = a2; nhbuf[r] = b2; }
        }
    }

    // ---- stage tap tile (no top halo, 5 left/right; rgb pre-scaled) ----
    for (int i = t; i < TLH * TLW; i += 256) {
        int lr = i / TLW;
        int lc = i - lr * TLW;
        int gy = y0 + lr;
        int gx = x0 + lc - 5;
        float4 v = make_float4(0.f, 0.f, 0.f, 0.f);
        if ((unsigned)gy < (unsigned)HH && (unsigned)gx < (unsigned)WW) {
            int gi = gy * WW + gx;
            v.x = fr[gi] * RGB_SCALE;
            v.y = fg[gi] * RGB_SCALE;
            v.z = fb[gi] * RGB_SCALE;
            v.w = ps[gi];
        }
        tile[lr * LSTRIDE + lc] = v;
    }
    __syncthreads();

    // ---- vertical 5-OR + q-position validity -> mask bits per row ----
    // mask(q)=1 iff dil=1 AND ero=0 <=> D & E (E = OR of valid ~lbl = 1-ero).
    if (t < 37) {
        int lo = 5 - x0; if (lo < 0) lo = 0;          // colmask: 0 <= x0-5+i < WW
        int hi = WW + 5 - x0; if (hi > 42) hi = 42;
        unsigned long long cm = ((1ull << hi) - 1) & ~((1ull << lo) - 1);
        unsigned long long D = hbuf[t], E = nhbuf[t];
        #pragma unroll
        for (int k = 1; k < 5; ++k) { D |= hbuf[t + k]; E |= nhbuf[t + k]; }
        Mbuf[t] = (y0 + t < HH) ? (D & E & cm) : 0ull;
    }
    __syncthreads();

    // ---- expand mask bits -> float plane (cols 0..41; 42-43 unused) ----
    for (int i = t; i < MH * MW; i += 256) {
        int mr = i / MW, mc = i - mr * MW;
        maskp[mr * MSTRIDE + mc] = (float)((Mbuf[mr] >> mc) & 1ull);
    }
    __syncthreads();

    // ---- half-window pair taps: each thread owns 4 x-adjacent pixels ----
    const int txq = t & 7;       // 0..7
    const int ty  = t >> 3;      // 0..31
    const int px0 = txq * 4;

    // trow[dy*LSTRIDE + j] = window col j (gx = x0+px0-5+j) of window row dy
    // (gy = y0+ty+dy). Centers at j = 5..8.
    const float4* trow = tile + ty * LSTRIDE + px0;
    const float*  mrow = maskp + ty * MSTRIDE + px0;   // mask col px0+j <-> window col j

    float4 c0 = trow[5], c1 = trow[6], c2 = trow[7], c3 = trow[8];
    f32x2 n01x = {-c0.x, -c1.x}, n01y = {-c0.y, -c1.y}, n01z = {-c0.z, -c1.z}, n01w = {-c0.w, -c1.w};
    f32x2 n23x = {-c2.x, -c3.x}, n23y = {-c2.y, -c3.y}, n23z = {-c2.z, -c3.z}, n23w = {-c2.w, -c3.w};

    f32x2 aP01 = {0.f, 0.f}, aP23 = {0.f, 0.f};
    f32x2 aQ01 = {0.f, 0.f}, aQ23 = {0.f, 0.f};
    float sP0 = 0.f, sP1 = 0.f, sP2 = 0.f, sP3 = 0.f, sQ = 0.f;

    // dy = 0 row: pairs to the RIGHT only (dx 1..5). Window cols j = 6..13.
    float4 mf0[3];
    #pragma unroll
    for (int q = 0; q < 3; ++q) mf0[q] = *(const float4*)&mrow[4 + 4 * q];
    {
        float4 w0[8];
        #pragma unroll
        for (int j = 0; j < 8; ++j) w0[j] = trow[6 + j];

        tap_scalar(w0[0], elem(mf0[0], 2), n01x.x, n01y.x, n01z.x, n01w.x, sP0, sQ); // c0 dx=1
        #pragma unroll
        for (int j = 1; j <= 4; ++j)  // c0 dx 2..5 / c1 dx 1..4
            tap_pair(w0[j], elem(mf0[(j + 2) >> 2], (j + 2) & 3), n01x, n01y, n01z, n01w, aP01, aQ01);
        tap_scalar(w0[5], elem(mf0[1], 3), n01x.y, n01y.y, n01z.y, n01w.y, sP1, sQ); // c1 dx=5
        tap_scalar(w0[2], elem(mf0[1], 0), n23x.x, n23y.x, n23z.x, n23w.x, sP2, sQ); // c2 dx=1
        #pragma unroll
        for (int j = 3; j <= 6; ++j)  // c2 dx 2..5 / c3 dx 1..4
            tap_pair(w0[j], elem(mf0[(j + 2) >> 2], (j + 2) & 3), n23x, n23y, n23z, n23w, aP23, aQ23);
        tap_scalar(w0[7], elem(mf0[2], 1), n23x.y, n23y.y, n23z.y, n23w.y, sP3, sQ); // c3 dx=5
    }

    // dy = 1..5 rows: full dx range [-5,5]. Window cols j = 0..13 (14 b128).
    // KEEP ROLLED (unroll 1): full unroll hoists ~70 float4 LDS loads ->
    // 280+ VGPR liveness -> scratch spill (R4: 8x slower).
    #pragma unroll 1
    for (int dy = 1; dy <= 5; ++dy) {
        float4 w[14];
        #pragma unroll
        for (int j = 0; j < 14; ++j) w[j] = trow[dy * LSTRIDE + j];
        float4 mf[4];
        const float* mro = mrow + dy * MSTRIDE;
        #pragma unroll
        for (int q = 0; q < 4; ++q) mf[q] = *(const float4*)&mro[4 * q];

        tap_scalar(w[0], elem(mf[0], 0), n01x.x, n01y.x, n01z.x, n01w.x, sP0, sQ); // c0 dx=-5
        #pragma unroll
        for (int j = 1; j <= 10; ++j)
            tap_pair(w[j], elem(mf[j >> 2], j & 3), n01x, n01y, n01z, n01w, aP01, aQ01);
        tap_scalar(w[11], elem(mf[2], 3), n01x.y, n01y.y, n01z.y, n01w.y, sP1, sQ); // c1 dx=+5
        tap_scalar(w[2],  elem(mf[0], 2), n23x.x, n23y.x, n23z.x, n23w.x, sP2, sQ); // c2 dx=-5
        #pragma unroll
        for (int j = 3; j <= 12; ++j)
            tap_pair(w[j], elem(mf[j >> 2], j & 3), n23x, n23y, n23z, n23w, aP23, aQ23);
        tap_scalar(w[13], elem(mf[3], 1), n23x.y, n23y.y, n23z.y, n23w.y, sP3, sQ); // c3 dx=+5
    }

    // ---- combine: num = sum_i m_i*(A_H(i) + pad_i) + sum(v*m_q) ----
    float m0 = mf0[0].y, m1 = mf0[0].z, m2 = mf0[0].w, m3 = mf0[1].x;
    float e0 = aP01.x + sP0, e1 = aP01.y + sP1;
    float e2 = aP23.x + sP2, e3 = aP23.y + sP3;

    // Upper/left pad taps (closed form): all pads identical for a pixel.
    const bool padblk = (ty_blk == 0) || (tx_blk == 0) || (tx_blk == TILES_X - 1);
    if (padblk) {
        const int gy = y0 + ty;
        const int nneg = (5 - gy) > 0 ? (5 - gy) : 0;   // # fully-pad rows above
        #pragma unroll
        for (int i = 0; i < 4; ++i) {
            const int gx = x0 + px0 + i;
            const int cl = (5 - gx) > 0 ? (5 - gx) : 0;
            const int cr = (gx - 346) > 0 ? (gx - 346) : 0;
            const int np = nneg * 11 + (5 - nneg) * (cl + cr) + cl;
            if (np > 0) {
                float4 ci = (i == 0) ? c0 : (i == 1) ? c1 : (i == 2) ? c2 : c3;
                float s2 = fmaf(ci.x, ci.x, fmaf(ci.y, ci.y, ci.z * ci.z));
                float vp = __builtin_amdgcn_exp2f(-s2) * ci.w * (float)np;
                if (i == 0) e0 += vp; else if (i == 1) e1 += vp;
                else if (i == 2) e2 += vp; else e3 += vp;
            }
        }
    }

    float num = fmaf(m0, e0, fmaf(m1, e1, fmaf(m2, e2, m3 * e3)))
              + ((aQ01.x + aQ01.y) + (aQ23.x + aQ23.y)) + sQ;
    float den = (m0 + m1) + (m2 + m3);

    // ---- wave reduce -> block reduce -> deterministic partial store ----
    #pragma unroll
    for (int off = 32; off > 0; off >>= 1) {
        num += __shfl_down(num, off, 64);
        den += __shfl_down(den, off, 64);
    }
    const int wid  = t >> 6;
    const int lane = t & 63;
    if (lane == 0) wred[wid] = make_float2(num, den);
    __syncthreads();
    if (t == 0) {
        float2 a = wred[0];
        #pragma unroll
        for (int w2 = 1; w2 < 4; ++w2) { a.x += wred[w2].x; a.y += wred[w2].y; }
        partials[bid] = a;
    }
}

__global__ __launch_bounds__(256)
void btm_finalize_kernel(const float2* __restrict__ partials,
                         float* __restrict__ out) {
    __shared__ float2 wred[4];
    float num = 0.f, den = 0.f;
    for (int i = threadIdx.x; i < NBLK; i += 256) {
        float2 p = partials[i];
        num += p.x;
        den += p.y;
    }
    #pragma unroll
    for (int off = 32; off > 0; off >>= 1) {
        num += __shfl_down(num, off, 64);
        den += __shfl_down(den, off, 64);
    }
    int wid  = threadIdx.x >> 6;
    int lane = threadIdx.x & 63;
    if (lane == 0) wred[wid] = make_float2(num, den);
    __syncthreads();
    if (threadIdx.x == 0) {
        float2 a = wred[0];
        #pragma unroll
        for (int w = 1; w < 4; ++w) { a.x += wred[w].x; a.y += wred[w].y; }
        out[0] = a.x / (a.y + 1e-6f);
    }
}

extern "C" void kernel_launch(void* const* d_in, const int* in_sizes, int n_in,
                              void* d_out, int out_size, void* d_ws, size_t ws_size,
                              hipStream_t stream) {
    const float* pred = (const float*)d_in[0];  // (8,1,352,352) fp32
    const float* feat = (const float*)d_in[1];  // (8,3,352,352) fp32
    float* out = (float*)d_out;                 // scalar fp32
    float2* partials = (float2*)d_ws;           // NBLK float2 = 7.7 KB

    btm_loss_kernel<<<dim3(NBLK), dim3(256), 0, stream>>>(pred, feat, partials);
    btm_finalize_kernel<<<dim3(1), dim3(256), 0, stream>>>(partials, out);
}

// Round 10
// 92.272 us; speedup vs baseline: 1.1827x; 1.0321x over previous
//
#include <hip/hip_runtime.h>

// Problem constants (match reference)
#define NB 8
#define HH 352
#define WW 352
#define TX 32
#define TY 32
// AoS tap tile: taps look down/sideways only -> rows gy in [y0, y0+36],
// cols gx in [x0-5, x0+36].
#define TLH 37
#define TLW 42
#define LSTRIDE 43               // float4 units, odd -> (3*row + col) mod 8 covers all bank quads
// mask plane: rows gy in [y0, y0+36], cols gx in [x0-5, x0+36]
#define MH 37
#define MW 42
#define MSTRIDE 44               // mult of 4 floats for aligned b128 reads
#define TILES_X 11
#define TILES_Y 11
#define NBLK (TILES_X * TILES_Y * NB)   // 968 = 8 XCDs x 121 tiles (one image each)

// Pre-scale rgb by sqrt(ALPHA * log2(e)) so wgt = exp2(-sum(d^2))
#define RGB_SCALE 16.98644781888824f

typedef float f32x2 __attribute__((ext_vector_type(2)));

__device__ __forceinline__ float elem(float4 q, int c) {
    return c == 0 ? q.x : c == 1 ? q.y : c == 2 ? q.z : q.w;
}

// One window float4 vs a PAIR of pre-negated packed centers, with mask-weight mq
// (mq = mask of the shared window pixel q). v = e*|ds| per tap;
// accP += v (m_p applied after the loop); accQ += v*mq.
__device__ __forceinline__ void tap_pair(const float4& w, float mq,
                                         f32x2 ncx, f32x2 ncy, f32x2 ncz, f32x2 ncw,
                                         f32x2& accP, f32x2& accQ) {
    f32x2 d0 = ncx + w.x;        // pk_add, scalar broadcast
    f32x2 d1 = ncy + w.y;
    f32x2 d2 = ncz + w.z;
    f32x2 s  = d0 * d0;
    s += d1 * d1;                // pk_fma
    s += d2 * d2;
    f32x2 ds = ncw + w.w;
    f32x2 v;
    v.x = __builtin_amdgcn_exp2f(-s.x) * fabsf(ds.x);
    v.y = __builtin_amdgcn_exp2f(-s.y) * fabsf(ds.y);
    accP += v;                   // pk_add
    f32x2 mqv; mqv.x = mq; mqv.y = mq;
    accQ += v * mqv;             // pk_fma
}

__device__ __forceinline__ void tap_scalar(const float4& w, float mq,
                                           float ncx, float ncy, float ncz, float ncw,
                                           float& aP, float& aQ) {
    float d0 = w.x + ncx, d1 = w.y + ncy, d2 = w.z + ncz;
    float s = fmaf(d0, d0, fmaf(d1, d1, d2 * d2));
    float v = __builtin_amdgcn_exp2f(-s) * fabsf(w.w + ncw);
    aP += v;
    aQ = fmaf(v, mq, aQ);
}

// LDS budget ~33 KB -> 4 blocks/CU by LDS. Launch bounds (256,2): R6 showed
// (256,4) forces a 64-VGPR cap -> scratch spills; (256,2) -> ~76 VGPR, no spill.
// Separate finalize kernel: R8 showed per-block cross-XCD fence costs ~14 us.
__global__ __launch_bounds__(256, 2)
void btm_loss_kernel(const float* __restrict__ pred,
                     const float* __restrict__ feat,
                     float2* __restrict__ partials) {
    __shared__ __align__(16) float4 tile[TLH * LSTRIDE];  // 25.4 KB AoS (r,g,b,sal)
    __shared__ __align__(16) float  maskp[MH * MSTRIDE];  // 6.5 KB mask plane
    __shared__ unsigned long long hbuf[41];               // horiz 5-OR of lbl bits
    __shared__ unsigned long long nhbuf[41];              // horiz 5-OR of ~lbl bits
    __shared__ unsigned long long Mbuf[37];               // final mask bits per row
    __shared__ float2 wred[4];

    // XCD-aware swizzle: dispatch assigns blockIdx round-robin to the 8 XCDs.
    // 968 = 8 x 121: give XCD k the 121 tiles of image k, so every halo re-read
    // hits that XCD's private L2 (2 MB of planes << 4 MB L2). FETCH ~2x input
    // without this (R9: 26.7 MB vs 14 MB input). partials[] is indexed by the
    // ORIGINAL bid -> finalize order, and output bits, unchanged.
    const int braw = blockIdx.x;
    const int bid  = (braw & 7) * (TILES_X * TILES_Y) + (braw >> 3);  // bijective
    const int tx_blk = bid % TILES_X;
    const int ty_blk = (bid / TILES_X) % TILES_Y;
    const int n = bid / (TILES_X * TILES_Y);
    const int x0 = tx_blk * TX;
    const int y0 = ty_blk * TY;

    const size_t plane = (size_t)HH * WW;
    const float* fr = feat + ((size_t)n * 3 + 0) * plane;
    const float* fg = feat + ((size_t)n * 3 + 1) * plane;
    const float* fb = feat + ((size_t)n * 3 + 2) * plane;
    const float* ps = pred + (size_t)n * plane;

    const int t = threadIdx.x;

    // ---- bit-mask build: one sal row per wave-iteration via ballot ----
    // Row r covers gy = y0+r-2, bit l covers gx = x0-7+l (l < 46). Validity is
    // folded into the ballot predicate (invalid -> contributes to neither OR,
    // matching maxpool's zero padding / ero's min-over-valid).
    {
        const int wv = t >> 6, ln = t & 63;
        for (int r = wv; r < 41; r += 4) {
            int gy = y0 + r - 2;
            int gx = x0 - 7 + ln;
            bool inimg = ((unsigned)gy < (unsigned)HH) &&
                         ((unsigned)gx < (unsigned)WW) && (ln < 46);
            float sv = inimg ? ps[gy * WW + gx] : 0.f;
            unsigned long long lb = __ballot(inimg && (sv > 0.5f));
            unsigned long long nb = __ballot(inimg && (sv <= 0.5f));
            // horizontal OR over bits i..i+4 (result bit i <-> mask col i)
            unsigned long long a2 = lb | (lb >> 1); a2 |= (a2 >> 2); a2 |= (lb >> 4);
            unsigned long long b2 = nb | (nb >> 1); b2 |= (b2 >> 2); b2 |= (nb >> 4);
            if (ln == 0) { hbuf[r] = a2; nhbuf[r] = b2; }
        }
    }

    // ---- stage tap tile (no top halo, 5 left/right; rgb pre-scaled) ----
    // Incremental row/col tracking (no per-iteration integer division).
    {
        int lr = t / TLW;
        int lc = t - lr * TLW;           // one division total; 256 % 42 pattern
        for (int i = t; i < TLH * TLW; i += 256) {
            int gy = y0 + lr;
            int gx = x0 + lc - 5;
            float4 v = make_float4(0.f, 0.f, 0.f, 0.f);
            if ((unsigned)gy < (unsigned)HH && (unsigned)gx < (unsigned)WW) {
                int gi = gy * WW + gx;
                v.x = fr[gi] * RGB_SCALE;
                v.y = fg[gi] * RGB_SCALE;
                v.z = fb[gi] * RGB_SCALE;
                v.w = ps[gi];
            }
            tile[lr * LSTRIDE + lc] = v;
            lc += 256 - 6 * TLW;         // 256 = 6*42 + 4
            lr += 6;
            if (lc >= TLW) { lc -= TLW; lr += 1; }
            else if (lc < 0) { lc += TLW; lr -= 1; }  // never taken (4 >= 0); keeps pattern general
        }
    }
    __syncthreads();

    // ---- vertical 5-OR + q-position validity -> mask bits per row ----
    // mask(q)=1 iff dil=1 AND ero=0 <=> D & E (E = OR of valid ~lbl = 1-ero).
    if (t < 37) {
        int lo = 5 - x0; if (lo < 0) lo = 0;          // colmask: 0 <= x0-5+i < WW
        int hi = WW + 5 - x0; if (hi > 42) hi = 42;
        unsigned long long cm = ((1ull << hi) - 1) & ~((1ull << lo) - 1);
        unsigned long long D = hbuf[t], E = nhbuf[t];
        #pragma unroll
        for (int k = 1; k < 5; ++k) { D |= hbuf[t + k]; E |= nhbuf[t + k]; }
        Mbuf[t] = (y0 + t < HH) ? (D & E & cm) : 0ull;
    }
    __syncthreads();

    // ---- expand mask bits -> float plane (cols 0..41; 42-43 unused) ----
    {
        int mr = t / MW;
        int mc = t - mr * MW;
        for (int i = t; i < MH * MW; i += 256) {
            maskp[mr * MSTRIDE + mc] = (float)((Mbuf[mr] >> mc) & 1ull);
            mc += 256 - 6 * MW;          // 256 = 6*42 + 4
            mr += 6;
            if (mc >= MW) { mc -= MW; mr += 1; }
        }
    }
    __syncthreads();

    // ---- half-window pair taps: each thread owns 4 x-adjacent pixels ----
    const int txq = t & 7;       // 0..7
    const int ty  = t >> 3;      // 0..31
    const int px0 = txq * 4;

    // trow[dy*LSTRIDE + j] = window col j (gx = x0+px0-5+j) of window row dy
    // (gy = y0+ty+dy). Centers at j = 5..8.
    const float4* trow = tile + ty * LSTRIDE + px0;
    const float*  mrow = maskp + ty * MSTRIDE + px0;   // mask col px0+j <-> window col j

    float4 c0 = trow[5], c1 = trow[6], c2 = trow[7], c3 = trow[8];
    f32x2 n01x = {-c0.x, -c1.x}, n01y = {-c0.y, -c1.y}, n01z = {-c0.z, -c1.z}, n01w = {-c0.w, -c1.w};
    f32x2 n23x = {-c2.x, -c3.x}, n23y = {-c2.y, -c3.y}, n23z = {-c2.z, -c3.z}, n23w = {-c2.w, -c3.w};

    f32x2 aP01 = {0.f, 0.f}, aP23 = {0.f, 0.f};
    f32x2 aQ01 = {0.f, 0.f}, aQ23 = {0.f, 0.f};
    float sP0 = 0.f, sP1 = 0.f, sP2 = 0.f, sP3 = 0.f, sQ = 0.f;

    // dy = 0 row: pairs to the RIGHT only (dx 1..5). Window cols j = 6..13.
    float4 mf0[3];
    #pragma unroll
    for (int q = 0; q < 3; ++q) mf0[q] = *(const float4*)&mrow[4 + 4 * q];
    {
        float4 w0[8];
        #pragma unroll
        for (int j = 0; j < 8; ++j) w0[j] = trow[6 + j];

        tap_scalar(w0[0], elem(mf0[0], 2), n01x.x, n01y.x, n01z.x, n01w.x, sP0, sQ); // c0 dx=1
        #pragma unroll
        for (int j = 1; j <= 4; ++j)  // c0 dx 2..5 / c1 dx 1..4
            tap_pair(w0[j], elem(mf0[(j + 2) >> 2], (j + 2) & 3), n01x, n01y, n01z, n01w, aP01, aQ01);
        tap_scalar(w0[5], elem(mf0[1], 3), n01x.y, n01y.y, n01z.y, n01w.y, sP1, sQ); // c1 dx=5
        tap_scalar(w0[2], elem(mf0[1], 0), n23x.x, n23y.x, n23z.x, n23w.x, sP2, sQ); // c2 dx=1
        #pragma unroll
        for (int j = 3; j <= 6; ++j)  // c2 dx 2..5 / c3 dx 1..4
            tap_pair(w0[j], elem(mf0[(j + 2) >> 2], (j + 2) & 3), n23x, n23y, n23z, n23w, aP23, aQ23);
        tap_scalar(w0[7], elem(mf0[2], 1), n23x.y, n23y.y, n23z.y, n23w.y, sP3, sQ); // c3 dx=5
    }

    // dy = 1..5 rows: full dx range [-5,5]. Window cols j = 0..13 (14 b128).
    // KEEP ROLLED (unroll 1): full unroll hoists ~70 float4 LDS loads ->
    // 280+ VGPR liveness -> scratch spill (R4: 8x slower).
    #pragma unroll 1
    for (int dy = 1; dy <= 5; ++dy) {
        float4 w[14];
        #pragma unroll
        for (int j = 0; j < 14; ++j) w[j] = trow[dy * LSTRIDE + j];
        float4 mf[4];
        const float* mro = mrow + dy * MSTRIDE;
        #pragma unroll
        for (int q = 0; q < 4; ++q) mf[q] = *(const float4*)&mro[4 * q];

        tap_scalar(w[0], elem(mf[0], 0), n01x.x, n01y.x, n01z.x, n01w.x, sP0, sQ); // c0 dx=-5
        #pragma unroll
        for (int j = 1; j <= 10; ++j)
            tap_pair(w[j], elem(mf[j >> 2], j & 3), n01x, n01y, n01z, n01w, aP01, aQ01);
        tap_scalar(w[11], elem(mf[2], 3), n01x.y, n01y.y, n01z.y, n01w.y, sP1, sQ); // c1 dx=+5
        tap_scalar(w[2],  elem(mf[0], 2), n23x.x, n23y.x, n23z.x, n23w.x, sP2, sQ); // c2 dx=-5
        #pragma unroll
        for (int j = 3; j <= 12; ++j)
            tap_pair(w[j], elem(mf[j >> 2], j & 3), n23x, n23y, n23z, n23w, aP23, aQ23);
        tap_scalar(w[13], elem(mf[3], 1), n23x.y, n23y.y, n23z.y, n23w.y, sP3, sQ); // c3 dx=+5
    }

    // ---- combine: num = sum_i m_i*(A_H(i) + pad_i) + sum(v*m_q) ----
    float m0 = mf0[0].y, m1 = mf0[0].z, m2 = mf0[0].w, m3 = mf0[1].x;
    float e0 = aP01.x + sP0, e1 = aP01.y + sP1;
    float e2 = aP23.x + sP2, e3 = aP23.y + sP3;

    // Upper/left pad taps (closed form): all pads identical for a pixel.
    const bool padblk = (ty_blk == 0) || (tx_blk == 0) || (tx_blk == TILES_X - 1);
    if (padblk) {
        const int gy = y0 + ty;
        const int nneg = (5 - gy) > 0 ? (5 - gy) : 0;   // # fully-pad rows above
        #pragma unroll
        for (int i = 0; i < 4; ++i) {
            const int gx = x0 + px0 + i;
            const int cl = (5 - gx) > 0 ? (5 - gx) : 0;
            const int cr = (gx - 346) > 0 ? (gx - 346) : 0;
            const int np = nneg * 11 + (5 - nneg) * (cl + cr) + cl;
            if (np > 0) {
                float4 ci = (i == 0) ? c0 : (i == 1) ? c1 : (i == 2) ? c2 : c3;
                float s2 = fmaf(ci.x, ci.x, fmaf(ci.y, ci.y, ci.z * ci.z));
                float vp = __builtin_amdgcn_exp2f(-s2) * ci.w * (float)np;
                if (i == 0) e0 += vp; else if (i == 1) e1 += vp;
                else if (i == 2) e2 += vp; else e3 += vp;
            }
        }
    }

    float num = fmaf(m0, e0, fmaf(m1, e1, fmaf(m2, e2, m3 * e3)))
              + ((aQ01.x + aQ01.y) + (aQ23.x + aQ23.y)) + sQ;
    float den = (m0 + m1) + (m2 + m3);

    // ---- wave reduce -> block reduce -> deterministic partial store ----
    #pragma unroll
    for (int off = 32; off > 0; off >>= 1) {
        num += __shfl_down(num, off, 64);
        den += __shfl_down(den, off, 64);
    }
    const int wid  = t >> 6;
    const int lane = t & 63;
    if (lane == 0) wred[wid] = make_float2(num, den);
    __syncthreads();
    if (t == 0) {
        float2 a = wred[0];
        #pragma unroll
        for (int w2 = 1; w2 < 4; ++w2) { a.x += wred[w2].x; a.y += wred[w2].y; }
        partials[bid] = a;   // ORIGINAL bid -> finalize order bit-identical
    }
}

__global__ __launch_bounds__(256)
void btm_finalize_kernel(const float2* __restrict__ partials,
                         float* __restrict__ out) {
    __shared__ float2 wred[4];
    float num = 0.f, den = 0.f;
    for (int i = threadIdx.x; i < NBLK; i += 256) {
        float2 p = partials[i];
        num += p.x;
        den += p.y;
    }
    #pragma unroll
    for (int off = 32; off > 0; off >>= 1) {
        num += __shfl_down(num, off, 64);
        den += __shfl_down(den, off, 64);
    }
    int wid  = threadIdx.x >> 6;
    int lane = threadIdx.x & 63;
    if (lane == 0) wred[wid] = make_float2(num, den);
    __syncthreads();
    if (threadIdx.x == 0) {
        float2 a = wred[0];
        #pragma unroll
        for (int w = 1; w < 4; ++w) { a.x += wred[w].x; a.y += wred[w].y; }
        out[0] = a.x / (a.y + 1e-6f);
    }
}

extern "C" void kernel_launch(void* const* d_in, const int* in_sizes, int n_in,
                              void* d_out, int out_size, void* d_ws, size_t ws_size,
                              hipStream_t stream) {
    const float* pred = (const float*)d_in[0];  // (8,1,352,352) fp32
    const float* feat = (const float*)d_in[1];  // (8,3,352,352) fp32
    float* out = (float*)d_out;                 // scalar fp32
    float2* partials = (float2*)d_ws;           // NBLK float2 = 7.7 KB

    btm_loss_kernel<<<dim3(NBLK), dim3(256), 0, stream>>>(pred, feat, partials);
    btm_finalize_kernel<<<dim3(1), dim3(256), 0, stream>>>(partials, out);
}